// Round 20
// baseline (128.157 us; speedup 1.0000x reference)
//
#include <hip/hip_runtime.h>
#include <hip/hip_bf16.h>

#define D_MODEL 1024
#define NHEADS  16
#define HEADD   64
#define SEQ     2048
#define PERIOD  4096
#define LOG2E   1.44269504088896340736f

typedef __attribute__((ext_vector_type(4)))  float f32x4;
typedef __attribute__((ext_vector_type(16))) float f32x16;
typedef __attribute__((ext_vector_type(4)))  float fvec4;
typedef __attribute__((ext_vector_type(8)))  short s16x8;
typedef __attribute__((ext_vector_type(4)))  short s16x4;
typedef __attribute__((ext_vector_type(2)))  int   i32x2;
typedef __attribute__((ext_vector_type(4)))  int   i32x4;

__device__ __forceinline__ short bf16_bits(float f) {
    union { float f; unsigned u; } v; v.f = f;
    unsigned r = v.u + 0x7FFFu + ((v.u >> 16) & 1u);   // RNE
    return (short)(r >> 16);
}

__device__ __forceinline__ int cvt_pk_bf16(float a, float b) {
    int r;
    asm("v_cvt_pk_bf16_f32 %0, %1, %2" : "=v"(r) : "v"(a), "v"(b));
    return r;
}

__device__ __forceinline__ float bf16_to_f32(short s) {
    return __int_as_float(((int)(unsigned short)s) << 16);
}

__device__ __forceinline__ float exp2_hw(float x) {
    float r;
    asm("v_exp_f32 %0, %1" : "=v"(r) : "v"(x));   // bare 2^x, no OCML range code
    return r;
}

__device__ __forceinline__ void gload_lds16(const void* g, void* l) {
    __builtin_amdgcn_global_load_lds(
        (const __attribute__((address_space(1))) void*)g,
        (__attribute__((address_space(3))) void*)l, 16, 0, 0);
}

// ---------------- fused prep: cvt_x | transpose_w4 | build_biasq ----------------
// grid 5376: [0,4096) cvt_x, [4096,5120) transpose_w (256 tiles x 4 weights), [5120,5376) biasq
__global__ void prep_all(const float* __restrict__ x,
                         const float* __restrict__ wq, const float* __restrict__ wk,
                         const float* __restrict__ wv, const float* __restrict__ wo,
                         const float* __restrict__ rb,
                         short* __restrict__ xb, short* __restrict__ wqkv,
                         short* __restrict__ wot, f32x4* __restrict__ bq4) {
    __shared__ float tile[64][65];
    int bid = blockIdx.x;
    int t = threadIdx.x;
    if (bid < 4096) {
        int i = bid * 256 + t;
        fvec4 v = ((const fvec4*)x)[i];
        s16x4 o;
        o.x = bf16_bits(v.x); o.y = bf16_bits(v.y);
        o.z = bf16_bits(v.z); o.w = bf16_bits(v.w);
        ((s16x4*)xb)[i] = o;
    } else if (bid < 5120) {
        int b2 = bid - 4096;
        int wsel = b2 >> 8;
        int bxy = b2 & 255;
        const float* src = wsel == 0 ? wq : (wsel == 1 ? wk : (wsel == 2 ? wv : wo));
        short* dst = wsel < 3 ? wqkv + wsel * 1024 * 1024 : wot;
        int bx = bxy & 15, by = bxy >> 4;
        int n0 = bx * 64, k0 = by * 64;
        int cr = t >> 4;
        int cc = (t & 15) * 4;
        for (int i = 0; i < 4; ++i) {
            int row = cr + i * 16;
            fvec4 v = *(const fvec4*)&src[(k0 + row) * D_MODEL + n0 + cc];
            tile[row][cc+0] = v.x; tile[row][cc+1] = v.y;
            tile[row][cc+2] = v.z; tile[row][cc+3] = v.w;
        }
        __syncthreads();
        for (int i = 0; i < 4; ++i) {
            int row = cr + i * 16;
            s16x4 o;
            o.x = bf16_bits(tile[cc+0][row]);
            o.y = bf16_bits(tile[cc+1][row]);
            o.z = bf16_bits(tile[cc+2][row]);
            o.w = bf16_bits(tile[cc+3][row]);
            *(s16x4*)&dst[(n0 + row) * D_MODEL + k0 + cc] = o;
        }
    } else {
        int id = (bid - 5120) * 256 + t;    // 0..65535 = h*4096 + a
        int h = id >> 12, a = id & 4095;
        f32x4 v;
        #pragma unroll
        for (int j = 0; j < 4; ++j)
            v[j] = rb[((a + j) & (PERIOD - 1)) * NHEADS + h] * LOG2E - 16.0f;
        bq4[id] = v;
    }
}

// ---------------- fused QKV GEMM (r16-proven) + direct transposed V output ----------------
__global__ __launch_bounds__(256, 3) void gemm_qkv(
    const short* __restrict__ A, const short* __restrict__ Bt,
    const float* __restrict__ biasq, const float* __restrict__ biask,
    const float* __restrict__ biasv,
    short* __restrict__ qb, short* __restrict__ kb, short* __restrict__ vt)
{
    __shared__ short As[2][128 * 64];   // 2 x 16 KB
    __shared__ short Bs[2][64 * 64];    // 2 x  8 KB
    int tid = threadIdx.x;
    int lane = tid & 63, wid = tid >> 6;
    int ln = lane & 15, g = lane >> 4;
    int wr = (wid >> 1) * 64, wc = (wid & 1) * 32;

    int bid = blockIdx.x;
    int xcd = bid & 7, slot = bid >> 3;        // slot 0..191
    int mb = xcd * 4 + (slot / 48);            // 0..31
    int nb = slot % 48;                        // 0..47
    int m0 = mb * 128, n0 = nb * 64;

    int wsel = n0 >> 10;                       // 0:q 1:k 2:v
    const float* bias = wsel == 0 ? biasq : (wsel == 1 ? biask : biasv);
    float osc = wsel == 0 ? (0.125f * LOG2E) : 1.0f;
    int ncol0 = n0 & 1023;

    f32x4 acc[4][2] = {};

    auto STAGE = [&](int kt, int bi) {
        #pragma unroll
        for (int i = 0; i < 4; ++i) {
            int idx = i * 256 + tid;
            int row = idx >> 3, ch = idx & 7;
            int gch = ch ^ (row & 7);
            gload_lds16(&A[(m0 + row) * 1024 + kt + gch * 8],
                        (char*)&As[bi][0] + (i * 256 + wid * 64) * 16);
        }
        #pragma unroll
        for (int i = 0; i < 2; ++i) {
            int idx = i * 256 + tid;
            int row = idx >> 3, ch = idx & 7;
            int gch = ch ^ (row & 7);
            gload_lds16(&Bt[(n0 + row) * 1024 + kt + gch * 8],
                        (char*)&Bs[bi][0] + (i * 256 + wid * 64) * 16);
        }
    };

    STAGE(0, 0);
    __syncthreads();

    for (int kt = 0; kt < 16; ++kt) {
        int bi = kt & 1;
        if (kt < 15) STAGE((kt + 1) * 64, bi ^ 1);

        s16x8 af[4][2], bfr[2][2];
        #pragma unroll
        for (int m = 0; m < 4; ++m) {
            int row = wr + m * 16 + ln;
            #pragma unroll
            for (int kc = 0; kc < 2; ++kc)
                af[m][kc] = *(const s16x8*)&As[bi][row * 64 + (((kc * 4 + g) ^ (row & 7)) * 8)];
        }
        #pragma unroll
        for (int n = 0; n < 2; ++n) {
            int row = wc + n * 16 + ln;
            #pragma unroll
            for (int kc = 0; kc < 2; ++kc)
                bfr[n][kc] = *(const s16x8*)&Bs[bi][row * 64 + (((kc * 4 + g) ^ (row & 7)) * 8)];
        }
        #pragma unroll
        for (int kc = 0; kc < 2; ++kc)
            #pragma unroll
            for (int m = 0; m < 4; ++m)
                #pragma unroll
                for (int n = 0; n < 2; ++n)
                    acc[m][n] = __builtin_amdgcn_mfma_f32_16x16x32_bf16(af[m][kc], bfr[n][kc], acc[m][n], 0, 0, 0);

        __syncthreads();
    }

    if (wsel == 2) {
        // direct transposed V: vt[(b*1024 + gc)*2048 + s0 + r], r contiguous
        #pragma unroll
        for (int m = 0; m < 4; ++m) {
            int gr0 = m0 + wr + m * 16 + g * 4;
            int b = gr0 >> 11, s0 = gr0 & 2047;
            #pragma unroll
            for (int n = 0; n < 2; ++n) {
                int gc = ncol0 + wc + n * 16 + ln;
                float bvv = bias[gc];
                i32x2 st;
                st[0] = cvt_pk_bf16(acc[m][n][0] + bvv, acc[m][n][1] + bvv);
                st[1] = cvt_pk_bf16(acc[m][n][2] + bvv, acc[m][n][3] + bvv);
                *(i32x2*)&vt[(b * 1024 + gc) * 2048 + s0] = st;
            }
        }
    } else {
        short* dst = wsel == 0 ? qb : kb;
        #pragma unroll
        for (int m = 0; m < 4; ++m) {
            int gr0 = m0 + wr + m * 16 + g * 4;
            #pragma unroll
            for (int n = 0; n < 2; ++n) {
                int gc = ncol0 + wc + n * 16 + ln;
                float bvv = bias[gc];
                #pragma unroll
                for (int r = 0; r < 4; ++r)
                    dst[(gr0 + r) * 1024 + gc] = bf16_bits((acc[m][n][r] + bvv) * osc);
            }
        }
    }
}

// ---------------- GEMM: C = A[M,1024]b @ Bt[n][k]b + bias (MODE 3: f32 out) ----------------
template<int MODE>
__global__ __launch_bounds__(256) void gemm_bias(
    const short* __restrict__ A, const short* __restrict__ Bt,
    const float* __restrict__ bias, void* __restrict__ Cout)
{
    __shared__ short As[2][128 * 64];
    __shared__ short Bs[2][64 * 64];
    int tid = threadIdx.x;
    int lane = tid & 63, wid = tid >> 6;
    int ln = lane & 15, g = lane >> 4;
    int wr = (wid >> 1) * 64, wc = (wid & 1) * 32;

    int bid = blockIdx.x;                 // 0..511
    int xcd = bid & 7, slot = bid >> 3;
    int mb = xcd * 4 + (slot >> 4);
    int nb = slot & 15;
    int m0 = mb * 128, n0 = nb * 64;

    f32x4 acc[4][2] = {};

    auto STAGE = [&](int kt, int bi) {
        #pragma unroll
        for (int i = 0; i < 4; ++i) {
            int idx = i * 256 + tid;
            int row = idx >> 3, ch = idx & 7;
            int gch = ch ^ (row & 7);
            gload_lds16(&A[(m0 + row) * 1024 + kt + gch * 8],
                        (char*)&As[bi][0] + (i * 256 + wid * 64) * 16);
        }
        #pragma unroll
        for (int i = 0; i < 2; ++i) {
            int idx = i * 256 + tid;
            int row = idx >> 3, ch = idx & 7;
            int gch = ch ^ (row & 7);
            gload_lds16(&Bt[(n0 + row) * 1024 + kt + gch * 8],
                        (char*)&Bs[bi][0] + (i * 256 + wid * 64) * 16);
        }
    };

    STAGE(0, 0);
    __syncthreads();

    for (int kt = 0; kt < 16; ++kt) {
        int bi = kt & 1;
        if (kt < 15) STAGE((kt + 1) * 64, bi ^ 1);

        s16x8 af[4][2], bfr[2][2];
        #pragma unroll
        for (int m = 0; m < 4; ++m) {
            int row = wr + m * 16 + ln;
            #pragma unroll
            for (int kc = 0; kc < 2; ++kc)
                af[m][kc] = *(const s16x8*)&As[bi][row * 64 + (((kc * 4 + g) ^ (row & 7)) * 8)];
        }
        #pragma unroll
        for (int n = 0; n < 2; ++n) {
            int row = wc + n * 16 + ln;
            #pragma unroll
            for (int kc = 0; kc < 2; ++kc)
                bfr[n][kc] = *(const s16x8*)&Bs[bi][row * 64 + (((kc * 4 + g) ^ (row & 7)) * 8)];
        }
        #pragma unroll
        for (int kc = 0; kc < 2; ++kc)
            #pragma unroll
            for (int m = 0; m < 4; ++m)
                #pragma unroll
                for (int n = 0; n < 2; ++n)
                    acc[m][n] = __builtin_amdgcn_mfma_f32_16x16x32_bf16(af[m][kc], bfr[n][kc], acc[m][n], 0, 0, 0);

        __syncthreads();
    }

    #pragma unroll
    for (int m = 0; m < 4; ++m) {
        int gr0 = m0 + wr + m * 16 + g * 4;
        #pragma unroll
        for (int n = 0; n < 2; ++n) {
            int gc = n0 + wc + n * 16 + ln;
            float bv = bias[gc];
            #pragma unroll
            for (int r = 0; r < 4; ++r) {
                int gr = gr0 + r;
                float v = acc[m][n][r] + bv;
                if (MODE == 0)      ((short*)Cout)[gr * 1024 + gc] = bf16_bits(v * (0.125f * LOG2E));
                else if (MODE == 1) ((short*)Cout)[gr * 1024 + gc] = bf16_bits(v);
                else                ((float*)Cout)[gr * 1024 + gc] = v;
            }
        }
    }
}

// ---------------- attention partial: l computed by ones-MFMA (VALU tree deleted) ----------------
// l[q] = sum_k P[k][q] = (ones)^T . P : one extra MFMA per ks-step with A = bf16 1.0s,
// accumulating into lacc across ALL tiles; lacc[0] per lane = l(qrow) at loop end.
// pb already interleaves both lane-halves (permlane repack), so no cross-half reduce.
__global__ __launch_bounds__(256, 2) void attn_partial(
    const short* __restrict__ qb,     // [4096][1024], pre-scaled by 0.125*log2e
    const short* __restrict__ kb,     // [4096][1024]
    const short* __restrict__ vt,     // [(b*1024+h*64+d)][2048]
    const f32x4* __restrict__ biasq,  // [16][4096], log2 domain, minus 16
    short* __restrict__ po,           // [2][4096][1024] bf16 partial O
    float* __restrict__ pl)           // [2][4096][16]  f32 partial l
{
    __shared__ short KV[2][2][64 * 64];   // [buf][0=K,1=V] = 32 KB

    int tid = threadIdx.x;
    int lane = tid & 63;
    int wid = tid >> 6;                   // 0..3
    int l31 = lane & 31, hi = lane >> 5;

    // XCD swizzle: all 32 blocks of one (h,b) pinned to one XCD (bijective: 8*4*32 = 1024)
    int bid = blockIdx.x;
    int xcd = bid & 7, slot = bid >> 3;   // 0..127
    int hb = xcd * 4 + (slot >> 5);       // 0..31
    int qt = (slot >> 1) & 15;
    int half = slot & 1;
    int h = hb & 15, b = hb >> 4;
    int q0 = qt * 128 + wid * 32;
    int qrow = q0 + l31;
    int kbase = half * 1024;

    // Q fragments (B-operand: col=q, k-contiguous)
    s16x8 aq[4];
    #pragma unroll
    for (int kk = 0; kk < 4; ++kk)
        aq[kk] = *(const s16x8*)&qb[(b * SEQ + qrow) * D_MODEL + h * HEADD + kk * 16 + hi * 8];

    const f32x4* bq = biasq + h * PERIOD;

    // all-ones bf16 A-operand for the l-MFMA
    i32x4 ones_i;
    ones_i[0] = 0x3F803F80; ones_i[1] = 0x3F803F80;
    ones_i[2] = 0x3F803F80; ones_i[3] = 0x3F803F80;
    s16x8 ones = __builtin_bit_cast(s16x8, ones_i);

    f32x16 ot[2] = {};
    f32x16 lacc = {};

    auto STAGE = [&](int k0, int bi) {   // k0 absolute key index
        #pragma unroll
        for (int i = 0; i < 2; ++i) {
            int idx = i * 256 + tid;
            int row = idx >> 3, ch = idx & 7;
            int gch = ch ^ ((row & 7) ^ ((row >> 3) & 3));
            gload_lds16(&kb[(b * SEQ + k0 + row) * D_MODEL + h * HEADD + gch * 8],
                        (char*)&KV[bi][0][0] + (i * 256 + wid * 64) * 16);
            gload_lds16(&vt[(b * D_MODEL + h * HEADD + row) * SEQ + k0 + gch * 8],
                        (char*)&KV[bi][1][0] + (i * 256 + wid * 64) * 16);
        }
    };

    STAGE(kbase, 0);
    __syncthreads();

    for (int kt = 0; kt < 16; ++kt) {
        int k0 = kbase + kt * 64;
        int bi = kt & 1;
        if (kt < 15) STAGE(k0 + 64, bi ^ 1);   // prefetch next K/V tile

        // bias gathers issued early (overlap MFMA)
        f32x4 bv[2][4];
        #pragma unroll
        for (int kt32 = 0; kt32 < 2; ++kt32)
            #pragma unroll
            for (int rq = 0; rq < 4; ++rq) {
                int kq = k0 + kt32 * 32 + rq * 8 + hi * 4;
                bv[kt32][rq] = bq[(qrow - kq - 3) & (PERIOD - 1)];
            }

        // S^T = K · Q^T  (rows=k, cols=q), log2 domain
        f32x16 s[2];
        const short* Ksp = &KV[bi][0][0];
        const short* Vsp = &KV[bi][1][0];
        __builtin_amdgcn_s_setprio(1);
        #pragma unroll
        for (int kt32 = 0; kt32 < 2; ++kt32) {
            f32x16 acc = {};
            int rowK = kt32 * 32 + l31;
            int swz = (rowK & 7) ^ ((rowK >> 3) & 3);
            #pragma unroll
            for (int kk = 0; kk < 4; ++kk) {
                s16x8 kf = *(const s16x8*)&Ksp[rowK * 64 + (((2 * kk + hi) ^ swz) * 8)];
                acc = __builtin_amdgcn_mfma_f32_32x32x16_bf16(kf, aq[kk], acc, 0, 0, 0);
            }
            s[kt32] = acc;
        }
        __builtin_amdgcn_s_setprio(0);

        // p = exp2(score + bias - 16): fixed-max softmax
        #pragma unroll
        for (int kt32 = 0; kt32 < 2; ++kt32)
            #pragma unroll
            for (int rq = 0; rq < 4; ++rq) {
                s[kt32][rq * 4 + 0] = exp2_hw(s[kt32][rq * 4 + 0] + bv[kt32][rq][3]);
                s[kt32][rq * 4 + 1] = exp2_hw(s[kt32][rq * 4 + 1] + bv[kt32][rq][2]);
                s[kt32][rq * 4 + 2] = exp2_hw(s[kt32][rq * 4 + 2] + bv[kt32][rq][1]);
                s[kt32][rq * 4 + 3] = exp2_hw(s[kt32][rq * 4 + 3] + bv[kt32][rq][0]);
            }

        // P repack via permlane32_swap (VALU, no LDS) + PV + l-MFMA
        #pragma unroll
        for (int kt32 = 0; kt32 < 2; ++kt32) {
            int pk[8];
            #pragma unroll
            for (int i = 0; i < 8; ++i)
                pk[i] = cvt_pk_bf16(s[kt32][2 * i], s[kt32][2 * i + 1]);
            #pragma unroll
            for (int ks = 0; ks < 2; ++ks) {
                int a0 = pk[ks * 4 + 0], a1 = pk[ks * 4 + 1];
                int b0 = pk[ks * 4 + 2], b1 = pk[ks * 4 + 3];
                i32x2 r0 = __builtin_amdgcn_permlane32_swap(a0, b0, false, false);
                i32x2 r1 = __builtin_amdgcn_permlane32_swap(a1, b1, false, false);
                i32x4 wi;
                wi[0] = r0[0];   // k = hi*8 + 0,1
                wi[1] = r1[0];   // k = hi*8 + 2,3
                wi[2] = r0[1];   // k = hi*8 + 4,5
                wi[3] = r1[1];   // k = hi*8 + 6,7
                s16x8 pb = __builtin_bit_cast(s16x8, wi);
                __builtin_amdgcn_s_setprio(1);
                #pragma unroll
                for (int dd = 0; dd < 2; ++dd) {
                    int rowV = dd * 32 + l31;
                    int swzV = (rowV & 7) ^ ((rowV >> 3) & 3);
                    int chV = kt32 * 4 + ks * 2 + hi;
                    s16x8 vf = *(const s16x8*)&Vsp[rowV * 64 + ((chV ^ swzV) * 8)];
                    ot[dd] = __builtin_amdgcn_mfma_f32_32x32x16_bf16(vf, pb, ot[dd], 0, 0, 0);
                }
                lacc = __builtin_amdgcn_mfma_f32_32x32x16_bf16(ones, pb, lacc, 0, 0, 0);
                __builtin_amdgcn_s_setprio(0);
            }
        }

        __syncthreads();   // prefetch landed; all readers done
    }

    // epilogue: write bf16 partials (no divide; merge kernel finishes)
    short* poH = po + half * (4096 * 1024);
    int obase = (b * SEQ + qrow) * D_MODEL + h * HEADD;
    #pragma unroll
    for (int dd = 0; dd < 2; ++dd)
        #pragma unroll
        for (int rq = 0; rq < 4; ++rq) {
            i32x2 st;
            st[0] = cvt_pk_bf16(ot[dd][rq * 4 + 0], ot[dd][rq * 4 + 1]);
            st[1] = cvt_pk_bf16(ot[dd][rq * 4 + 2], ot[dd][rq * 4 + 3]);
            *(i32x2*)&poH[obase + dd * 32 + rq * 8 + hi * 4] = st;
        }
    if (hi == 0)
        pl[half * (4096 * 16) + (b * SEQ + qrow) * 16 + h] = lacc[0];
}

// ---------------- merge: ao = (po0+po1)/(pl0+pl1) -> bf16 ----------------
__global__ __launch_bounds__(256) void attn_merge(
    const short* __restrict__ po, const float* __restrict__ pl,
    short* __restrict__ ao)
{
    int idx = blockIdx.x * 256 + threadIdx.x;
    int base = idx * 8;                 // 8 consecutive cols, never crosses a head
    int row = base >> 10, col = base & 1023, h = col >> 6;
    float l = pl[row * 16 + h] + pl[4096 * 16 + row * 16 + h];
    float inv = 1.0f / l;
    s16x8 a = *(const s16x8*)&po[row * 1024 + col];
    s16x8 c = *(const s16x8*)&po[4096 * 1024 + row * 1024 + col];
    float v[8];
    #pragma unroll
    for (int j = 0; j < 8; ++j)
        v[j] = (bf16_to_f32(a[j]) + bf16_to_f32(c[j])) * inv;
    i32x4 o;
    o[0] = cvt_pk_bf16(v[0], v[1]);
    o[1] = cvt_pk_bf16(v[2], v[3]);
    o[2] = cvt_pk_bf16(v[4], v[5]);
    o[3] = cvt_pk_bf16(v[6], v[7]);
    *(i32x4*)&ao[base] = o;
}

extern "C" void kernel_launch(void* const* d_in, const int* in_sizes, int n_in,
                              void* d_out, int out_size, void* d_ws, size_t ws_size,
                              hipStream_t stream) {
    const float* x  = (const float*)d_in[0];
    const float* wq = (const float*)d_in[1];
    const float* bq = (const float*)d_in[2];
    const float* wk = (const float*)d_in[3];
    const float* bk = (const float*)d_in[4];
    const float* wv = (const float*)d_in[5];
    const float* bv = (const float*)d_in[6];
    const float* wo = (const float*)d_in[7];
    const float* bo = (const float*)d_in[8];
    const float* rb = (const float*)d_in[9];

    char* ws = (char*)d_ws;
    short* xb   = (short*)(ws);                 // 8 MB (reused as ao after attention)
    short* wqkv = (short*)(ws + (8u  << 20));   // 6 MB = wqt|wkt|wvt contiguous
    short* wot  = (short*)(ws + (14u << 20));   // 2 MB
    short* qb   = (short*)(ws + (16u << 20));   // 8 MB
    short* kb   = (short*)(ws + (24u << 20));   // 8 MB
    f32x4* bqt  = (f32x4*)(ws + (32u << 20));   // 1 MB
    short* vt   = (short*)(ws + (40u << 20));   // 8 MB (written directly by gemm_qkv)
    short* po   = (short*)(ws + (48u << 20));   // 16 MB bf16 partial O [2][4096][1024]
    float* pl   = (float*)(ws + (64u << 20));   // 512 KB f32 partial l [2][4096][16]
    short* ao   = xb;

    prep_all<<<5376, 256, 0, stream>>>(x, wq, wk, wv, wo, rb, xb, wqkv, wot, bqt);

    gemm_qkv<<<1536, 256, 0, stream>>>(xb, wqkv, bq, bk, bv, qb, kb, vt);

    attn_partial<<<1024, 256, 0, stream>>>(qb, kb, vt, bqt, po, pl);
    attn_merge<<<2048, 256, 0, stream>>>(po, pl, ao);

    gemm_bias<3><<<512, 256, 0, stream>>>(ao, wot, bo, (float*)d_out);
}

// Round 21
// 127.359 us; speedup vs baseline: 1.0063x; 1.0063x over previous
//
#include <hip/hip_runtime.h>
#include <hip/hip_bf16.h>

#define D_MODEL 1024
#define NHEADS  16
#define HEADD   64
#define SEQ     2048
#define PERIOD  4096
#define LOG2E   1.44269504088896340736f

typedef __attribute__((ext_vector_type(4)))  float f32x4;
typedef __attribute__((ext_vector_type(16))) float f32x16;
typedef __attribute__((ext_vector_type(4)))  float fvec4;
typedef __attribute__((ext_vector_type(8)))  short s16x8;
typedef __attribute__((ext_vector_type(4)))  short s16x4;
typedef __attribute__((ext_vector_type(2)))  int   i32x2;
typedef __attribute__((ext_vector_type(4)))  int   i32x4;

__device__ __forceinline__ short bf16_bits(float f) {
    union { float f; unsigned u; } v; v.f = f;
    unsigned r = v.u + 0x7FFFu + ((v.u >> 16) & 1u);   // RNE
    return (short)(r >> 16);
}

__device__ __forceinline__ int cvt_pk_bf16(float a, float b) {
    int r;
    asm("v_cvt_pk_bf16_f32 %0, %1, %2" : "=v"(r) : "v"(a), "v"(b));
    return r;
}

__device__ __forceinline__ float bf16_to_f32(short s) {
    return __int_as_float(((int)(unsigned short)s) << 16);
}

__device__ __forceinline__ float exp2_hw(float x) {
    float r;
    asm("v_exp_f32 %0, %1" : "=v"(r) : "v"(x));   // bare 2^x, no OCML range code
    return r;
}

__device__ __forceinline__ void gload_lds16(const void* g, void* l) {
    __builtin_amdgcn_global_load_lds(
        (const __attribute__((address_space(1))) void*)g,
        (__attribute__((address_space(3))) void*)l, 16, 0, 0);
}

// ---------------- fused prep: cvt_x | transpose_w4 | build_biasq ----------------
// grid 5376: [0,4096) cvt_x, [4096,5120) transpose_w (256 tiles x 4 weights), [5120,5376) biasq
__global__ void prep_all(const float* __restrict__ x,
                         const float* __restrict__ wq, const float* __restrict__ wk,
                         const float* __restrict__ wv, const float* __restrict__ wo,
                         const float* __restrict__ rb,
                         short* __restrict__ xb, short* __restrict__ wqkv,
                         short* __restrict__ wot, f32x4* __restrict__ bq4) {
    __shared__ float tile[64][65];
    int bid = blockIdx.x;
    int t = threadIdx.x;
    if (bid < 4096) {
        int i = bid * 256 + t;
        fvec4 v = ((const fvec4*)x)[i];
        s16x4 o;
        o.x = bf16_bits(v.x); o.y = bf16_bits(v.y);
        o.z = bf16_bits(v.z); o.w = bf16_bits(v.w);
        ((s16x4*)xb)[i] = o;
    } else if (bid < 5120) {
        int b2 = bid - 4096;
        int wsel = b2 >> 8;
        int bxy = b2 & 255;
        const float* src = wsel == 0 ? wq : (wsel == 1 ? wk : (wsel == 2 ? wv : wo));
        short* dst = wsel < 3 ? wqkv + wsel * 1024 * 1024 : wot;
        int bx = bxy & 15, by = bxy >> 4;
        int n0 = bx * 64, k0 = by * 64;
        int cr = t >> 4;
        int cc = (t & 15) * 4;
        for (int i = 0; i < 4; ++i) {
            int row = cr + i * 16;
            fvec4 v = *(const fvec4*)&src[(k0 + row) * D_MODEL + n0 + cc];
            tile[row][cc+0] = v.x; tile[row][cc+1] = v.y;
            tile[row][cc+2] = v.z; tile[row][cc+3] = v.w;
        }
        __syncthreads();
        for (int i = 0; i < 4; ++i) {
            int row = cr + i * 16;
            s16x4 o;
            o.x = bf16_bits(tile[cc+0][row]);
            o.y = bf16_bits(tile[cc+1][row]);
            o.z = bf16_bits(tile[cc+2][row]);
            o.w = bf16_bits(tile[cc+3][row]);
            *(s16x4*)&dst[(n0 + row) * D_MODEL + k0 + cc] = o;
        }
    } else {
        int id = (bid - 5120) * 256 + t;    // 0..65535 = h*4096 + a
        int h = id >> 12, a = id & 4095;
        f32x4 v;
        #pragma unroll
        for (int j = 0; j < 4; ++j)
            v[j] = rb[((a + j) & (PERIOD - 1)) * NHEADS + h] * LOG2E - 16.0f;
        bq4[id] = v;
    }
}

// ---------------- fused QKV GEMM (r16-proven) + direct transposed V output ----------------
__global__ __launch_bounds__(256, 3) void gemm_qkv(
    const short* __restrict__ A, const short* __restrict__ Bt,
    const float* __restrict__ biasq, const float* __restrict__ biask,
    const float* __restrict__ biasv,
    short* __restrict__ qb, short* __restrict__ kb, short* __restrict__ vt)
{
    __shared__ short As[2][128 * 64];   // 2 x 16 KB
    __shared__ short Bs[2][64 * 64];    // 2 x  8 KB
    int tid = threadIdx.x;
    int lane = tid & 63, wid = tid >> 6;
    int ln = lane & 15, g = lane >> 4;
    int wr = (wid >> 1) * 64, wc = (wid & 1) * 32;

    int bid = blockIdx.x;
    int xcd = bid & 7, slot = bid >> 3;        // slot 0..191
    int mb = xcd * 4 + (slot / 48);            // 0..31
    int nb = slot % 48;                        // 0..47
    int m0 = mb * 128, n0 = nb * 64;

    int wsel = n0 >> 10;                       // 0:q 1:k 2:v
    const float* bias = wsel == 0 ? biasq : (wsel == 1 ? biask : biasv);
    float osc = wsel == 0 ? (0.125f * LOG2E) : 1.0f;
    int ncol0 = n0 & 1023;

    f32x4 acc[4][2] = {};

    auto STAGE = [&](int kt, int bi) {
        #pragma unroll
        for (int i = 0; i < 4; ++i) {
            int idx = i * 256 + tid;
            int row = idx >> 3, ch = idx & 7;
            int gch = ch ^ (row & 7);
            gload_lds16(&A[(m0 + row) * 1024 + kt + gch * 8],
                        (char*)&As[bi][0] + (i * 256 + wid * 64) * 16);
        }
        #pragma unroll
        for (int i = 0; i < 2; ++i) {
            int idx = i * 256 + tid;
            int row = idx >> 3, ch = idx & 7;
            int gch = ch ^ (row & 7);
            gload_lds16(&Bt[(n0 + row) * 1024 + kt + gch * 8],
                        (char*)&Bs[bi][0] + (i * 256 + wid * 64) * 16);
        }
    };

    STAGE(0, 0);
    __syncthreads();

    for (int kt = 0; kt < 16; ++kt) {
        int bi = kt & 1;
        if (kt < 15) STAGE((kt + 1) * 64, bi ^ 1);

        s16x8 af[4][2], bfr[2][2];
        #pragma unroll
        for (int m = 0; m < 4; ++m) {
            int row = wr + m * 16 + ln;
            #pragma unroll
            for (int kc = 0; kc < 2; ++kc)
                af[m][kc] = *(const s16x8*)&As[bi][row * 64 + (((kc * 4 + g) ^ (row & 7)) * 8)];
        }
        #pragma unroll
        for (int n = 0; n < 2; ++n) {
            int row = wc + n * 16 + ln;
            #pragma unroll
            for (int kc = 0; kc < 2; ++kc)
                bfr[n][kc] = *(const s16x8*)&Bs[bi][row * 64 + (((kc * 4 + g) ^ (row & 7)) * 8)];
        }
        #pragma unroll
        for (int kc = 0; kc < 2; ++kc)
            #pragma unroll
            for (int m = 0; m < 4; ++m)
                #pragma unroll
                for (int n = 0; n < 2; ++n)
                    acc[m][n] = __builtin_amdgcn_mfma_f32_16x16x32_bf16(af[m][kc], bfr[n][kc], acc[m][n], 0, 0, 0);

        __syncthreads();
    }

    if (wsel == 2) {
        // direct transposed V: vt[(b*1024 + gc)*2048 + s0 + r], r contiguous
        #pragma unroll
        for (int m = 0; m < 4; ++m) {
            int gr0 = m0 + wr + m * 16 + g * 4;
            int b = gr0 >> 11, s0 = gr0 & 2047;
            #pragma unroll
            for (int n = 0; n < 2; ++n) {
                int gc = ncol0 + wc + n * 16 + ln;
                float bvv = bias[gc];
                i32x2 st;
                st[0] = cvt_pk_bf16(acc[m][n][0] + bvv, acc[m][n][1] + bvv);
                st[1] = cvt_pk_bf16(acc[m][n][2] + bvv, acc[m][n][3] + bvv);
                *(i32x2*)&vt[(b * 1024 + gc) * 2048 + s0] = st;
            }
        }
    } else {
        short* dst = wsel == 0 ? qb : kb;
        #pragma unroll
        for (int m = 0; m < 4; ++m) {
            int gr0 = m0 + wr + m * 16 + g * 4;
            #pragma unroll
            for (int n = 0; n < 2; ++n) {
                int gc = ncol0 + wc + n * 16 + ln;
                float bvv = bias[gc];
                #pragma unroll
                for (int r = 0; r < 4; ++r)
                    dst[(gr0 + r) * 1024 + gc] = bf16_bits((acc[m][n][r] + bvv) * osc);
            }
        }
    }
}

// ---------------- GEMM: C = A[M,1024]b @ Bt[n][k]b + bias (MODE 3: f32 out) ----------------
template<int MODE>
__global__ __launch_bounds__(256) void gemm_bias(
    const short* __restrict__ A, const short* __restrict__ Bt,
    const float* __restrict__ bias, void* __restrict__ Cout)
{
    __shared__ short As[2][128 * 64];
    __shared__ short Bs[2][64 * 64];
    int tid = threadIdx.x;
    int lane = tid & 63, wid = tid >> 6;
    int ln = lane & 15, g = lane >> 4;
    int wr = (wid >> 1) * 64, wc = (wid & 1) * 32;

    int bid = blockIdx.x;                 // 0..511
    int xcd = bid & 7, slot = bid >> 3;
    int mb = xcd * 4 + (slot >> 4);
    int nb = slot & 15;
    int m0 = mb * 128, n0 = nb * 64;

    f32x4 acc[4][2] = {};

    auto STAGE = [&](int kt, int bi) {
        #pragma unroll
        for (int i = 0; i < 4; ++i) {
            int idx = i * 256 + tid;
            int row = idx >> 3, ch = idx & 7;
            int gch = ch ^ (row & 7);
            gload_lds16(&A[(m0 + row) * 1024 + kt + gch * 8],
                        (char*)&As[bi][0] + (i * 256 + wid * 64) * 16);
        }
        #pragma unroll
        for (int i = 0; i < 2; ++i) {
            int idx = i * 256 + tid;
            int row = idx >> 3, ch = idx & 7;
            int gch = ch ^ (row & 7);
            gload_lds16(&Bt[(n0 + row) * 1024 + kt + gch * 8],
                        (char*)&Bs[bi][0] + (i * 256 + wid * 64) * 16);
        }
    };

    STAGE(0, 0);
    __syncthreads();

    for (int kt = 0; kt < 16; ++kt) {
        int bi = kt & 1;
        if (kt < 15) STAGE((kt + 1) * 64, bi ^ 1);

        s16x8 af[4][2], bfr[2][2];
        #pragma unroll
        for (int m = 0; m < 4; ++m) {
            int row = wr + m * 16 + ln;
            #pragma unroll
            for (int kc = 0; kc < 2; ++kc)
                af[m][kc] = *(const s16x8*)&As[bi][row * 64 + (((kc * 4 + g) ^ (row & 7)) * 8)];
        }
        #pragma unroll
        for (int n = 0; n < 2; ++n) {
            int row = wc + n * 16 + ln;
            #pragma unroll
            for (int kc = 0; kc < 2; ++kc)
                bfr[n][kc] = *(const s16x8*)&Bs[bi][row * 64 + (((kc * 4 + g) ^ (row & 7)) * 8)];
        }
        #pragma unroll
        for (int kc = 0; kc < 2; ++kc)
            #pragma unroll
            for (int m = 0; m < 4; ++m)
                #pragma unroll
                for (int n = 0; n < 2; ++n)
                    acc[m][n] = __builtin_amdgcn_mfma_f32_16x16x32_bf16(af[m][kc], bfr[n][kc], acc[m][n], 0, 0, 0);

        __syncthreads();
    }

    #pragma unroll
    for (int m = 0; m < 4; ++m) {
        int gr0 = m0 + wr + m * 16 + g * 4;
        #pragma unroll
        for (int n = 0; n < 2; ++n) {
            int gc = n0 + wc + n * 16 + ln;
            float bv = bias[gc];
            #pragma unroll
            for (int r = 0; r < 4; ++r) {
                int gr = gr0 + r;
                float v = acc[m][n][r] + bv;
                if (MODE == 0)      ((short*)Cout)[gr * 1024 + gc] = bf16_bits(v * (0.125f * LOG2E));
                else if (MODE == 1) ((short*)Cout)[gr * 1024 + gc] = bf16_bits(v);
                else                ((float*)Cout)[gr * 1024 + gc] = v;
            }
        }
    }
}

// ---------------- attention partial: r19 form + entry s_sleep de-phase (convoy A/B) ----------------
// r20 lesson: pipes are ~serialized (VALU 37 + MFMA 28 + LDS ~35 ≈ 100%); co-resident
// blocks convoy through identical phases. One-time stagger keyed on bid>>8 (co-resident
// set under round-robin dispatch) offsets them by ~1/6 tile each. s_sleep is pure delay.
__global__ __launch_bounds__(256, 2) void attn_partial(
    const short* __restrict__ qb,     // [4096][1024], pre-scaled by 0.125*log2e
    const short* __restrict__ kb,     // [4096][1024]
    const short* __restrict__ vt,     // [(b*1024+h*64+d)][2048]
    const f32x4* __restrict__ biasq,  // [16][4096], log2 domain, minus 16
    short* __restrict__ po,           // [2][4096][1024] bf16 partial O
    float* __restrict__ pl)           // [2][4096][16]  f32 partial l
{
    __shared__ short KV[2][2][64 * 64];   // [buf][0=K,1=V] = 32 KB

    int tid = threadIdx.x;
    int lane = tid & 63;
    int wid = tid >> 6;                   // 0..3
    int l31 = lane & 31, hi = lane >> 5;

    // XCD swizzle: all 32 blocks of one (h,b) pinned to one XCD (bijective: 8*4*32 = 1024)
    int bid = blockIdx.x;
    int xcd = bid & 7, slot = bid >> 3;   // 0..127
    int hb = xcd * 4 + (slot >> 5);       // 0..31
    int qt = (slot >> 1) & 15;
    int half = slot & 1;
    int h = hb & 15, b = hb >> 4;
    int q0 = qt * 128 + wid * 32;
    int qrow = q0 + l31;
    int kbase = half * 1024;

    // Q fragments (B-operand: col=q, k-contiguous)
    s16x8 aq[4];
    #pragma unroll
    for (int kk = 0; kk < 4; ++kk)
        aq[kk] = *(const s16x8*)&qb[(b * SEQ + qrow) * D_MODEL + h * HEADD + kk * 16 + hi * 8];

    const f32x4* bq = biasq + h * PERIOD;

    float lrow = 0.f;
    f32x16 ot[2] = {};

    auto STAGE = [&](int k0, int bi) {   // k0 absolute key index
        #pragma unroll
        for (int i = 0; i < 2; ++i) {
            int idx = i * 256 + tid;
            int row = idx >> 3, ch = idx & 7;
            int gch = ch ^ ((row & 7) ^ ((row >> 3) & 3));
            gload_lds16(&kb[(b * SEQ + k0 + row) * D_MODEL + h * HEADD + gch * 8],
                        (char*)&KV[bi][0][0] + (i * 256 + wid * 64) * 16);
            gload_lds16(&vt[(b * D_MODEL + h * HEADD + row) * SEQ + k0 + gch * 8],
                        (char*)&KV[bi][1][0] + (i * 256 + wid * 64) * 16);
        }
    };

    STAGE(kbase, 0);
    // de-phase co-resident blocks (bid, bid+256, +512, +768 share a CU under
    // round-robin dispatch): one-time pure delay, ~384 cyc per step
    {
        int ph = (bid >> 8) & 3;
        if (ph == 1) asm volatile("s_sleep 6");
        if (ph == 2) asm volatile("s_sleep 12");
        if (ph == 3) asm volatile("s_sleep 18");
    }
    __syncthreads();

    for (int kt = 0; kt < 16; ++kt) {
        int k0 = kbase + kt * 64;
        int bi = kt & 1;
        if (kt < 15) STAGE(k0 + 64, bi ^ 1);   // prefetch next K/V tile

        // bias gathers issued early (overlap MFMA)
        f32x4 bv[2][4];
        #pragma unroll
        for (int kt32 = 0; kt32 < 2; ++kt32)
            #pragma unroll
            for (int rq = 0; rq < 4; ++rq) {
                int kq = k0 + kt32 * 32 + rq * 8 + hi * 4;
                bv[kt32][rq] = bq[(qrow - kq - 3) & (PERIOD - 1)];
            }

        // S^T = K · Q^T  (rows=k, cols=q), log2 domain
        f32x16 s[2];
        const short* Ksp = &KV[bi][0][0];
        const short* Vsp = &KV[bi][1][0];
        __builtin_amdgcn_s_setprio(1);
        #pragma unroll
        for (int kt32 = 0; kt32 < 2; ++kt32) {
            f32x16 acc = {};
            int rowK = kt32 * 32 + l31;
            int swz = (rowK & 7) ^ ((rowK >> 3) & 3);
            #pragma unroll
            for (int kk = 0; kk < 4; ++kk) {
                s16x8 kf = *(const s16x8*)&Ksp[rowK * 64 + (((2 * kk + hi) ^ swz) * 8)];
                acc = __builtin_amdgcn_mfma_f32_32x32x16_bf16(kf, aq[kk], acc, 0, 0, 0);
            }
            s[kt32] = acc;
        }
        __builtin_amdgcn_s_setprio(0);

        // p = exp2(score + bias - 16): fixed-max softmax
        #pragma unroll
        for (int kt32 = 0; kt32 < 2; ++kt32)
            #pragma unroll
            for (int rq = 0; rq < 4; ++rq) {
                s[kt32][rq * 4 + 0] = exp2_hw(s[kt32][rq * 4 + 0] + bv[kt32][rq][3]);
                s[kt32][rq * 4 + 1] = exp2_hw(s[kt32][rq * 4 + 1] + bv[kt32][rq][2]);
                s[kt32][rq * 4 + 2] = exp2_hw(s[kt32][rq * 4 + 2] + bv[kt32][rq][1]);
                s[kt32][rq * 4 + 3] = exp2_hw(s[kt32][rq * 4 + 3] + bv[kt32][rq][0]);
            }

        // l accumulation: tree over 32 in-lane values + cross-half partner add
        float sm[16];
        #pragma unroll
        for (int t = 0; t < 16; ++t) sm[t] = s[0][t] + s[1][t];
        #pragma unroll
        for (int t = 0; t < 8; ++t) sm[t] += sm[t + 8];
        #pragma unroll
        for (int t = 0; t < 4; ++t) sm[t] += sm[t + 4];
        float psum = (sm[0] + sm[1]) + (sm[2] + sm[3]);
        {
            i32x2 r = __builtin_amdgcn_permlane32_swap(__float_as_int(psum), __float_as_int(psum), false, false);
            psum = __int_as_float(r[0]) + __int_as_float(r[1]);
        }
        lrow += psum;

        // P repack via permlane32_swap (VALU, no LDS) + PV: O^T += V^T . P
        #pragma unroll
        for (int kt32 = 0; kt32 < 2; ++kt32) {
            int pk[8];
            #pragma unroll
            for (int i = 0; i < 8; ++i)
                pk[i] = cvt_pk_bf16(s[kt32][2 * i], s[kt32][2 * i + 1]);
            #pragma unroll
            for (int ks = 0; ks < 2; ++ks) {
                int a0 = pk[ks * 4 + 0], a1 = pk[ks * 4 + 1];
                int b0 = pk[ks * 4 + 2], b1 = pk[ks * 4 + 3];
                i32x2 r0 = __builtin_amdgcn_permlane32_swap(a0, b0, false, false);
                i32x2 r1 = __builtin_amdgcn_permlane32_swap(a1, b1, false, false);
                i32x4 wi;
                wi[0] = r0[0];   // k = hi*8 + 0,1
                wi[1] = r1[0];   // k = hi*8 + 2,3
                wi[2] = r0[1];   // k = hi*8 + 4,5
                wi[3] = r1[1];   // k = hi*8 + 6,7
                s16x8 pb = __builtin_bit_cast(s16x8, wi);
                __builtin_amdgcn_s_setprio(1);
                #pragma unroll
                for (int dd = 0; dd < 2; ++dd) {
                    int rowV = dd * 32 + l31;
                    int swzV = (rowV & 7) ^ ((rowV >> 3) & 3);
                    int chV = kt32 * 4 + ks * 2 + hi;
                    s16x8 vf = *(const s16x8*)&Vsp[rowV * 64 + ((chV ^ swzV) * 8)];
                    ot[dd] = __builtin_amdgcn_mfma_f32_32x32x16_bf16(vf, pb, ot[dd], 0, 0, 0);
                }
                __builtin_amdgcn_s_setprio(0);
            }
        }

        __syncthreads();   // prefetch landed; all readers done
    }

    // epilogue: write bf16 partials (no divide; merge kernel finishes)
    short* poH = po + half * (4096 * 1024);
    int obase = (b * SEQ + qrow) * D_MODEL + h * HEADD;
    #pragma unroll
    for (int dd = 0; dd < 2; ++dd)
        #pragma unroll
        for (int rq = 0; rq < 4; ++rq) {
            i32x2 st;
            st[0] = cvt_pk_bf16(ot[dd][rq * 4 + 0], ot[dd][rq * 4 + 1]);
            st[1] = cvt_pk_bf16(ot[dd][rq * 4 + 2], ot[dd][rq * 4 + 3]);
            *(i32x2*)&poH[obase + dd * 32 + rq * 8 + hi * 4] = st;
        }
    if (hi == 0)
        pl[half * (4096 * 16) + (b * SEQ + qrow) * 16 + h] = lrow;
}

// ---------------- merge: ao = (po0+po1)/(pl0+pl1) -> bf16 ----------------
__global__ __launch_bounds__(256) void attn_merge(
    const short* __restrict__ po, const float* __restrict__ pl,
    short* __restrict__ ao)
{
    int idx = blockIdx.x * 256 + threadIdx.x;
    int base = idx * 8;                 // 8 consecutive cols, never crosses a head
    int row = base >> 10, col = base & 1023, h = col >> 6;
    float l = pl[row * 16 + h] + pl[4096 * 16 + row * 16 + h];
    float inv = 1.0f / l;
    s16x8 a = *(const s16x8*)&po[row * 1024 + col];
    s16x8 c = *(const s16x8*)&po[4096 * 1024 + row * 1024 + col];
    float v[8];
    #pragma unroll
    for (int j = 0; j < 8; ++j)
        v[j] = (bf16_to_f32(a[j]) + bf16_to_f32(c[j])) * inv;
    i32x4 o;
    o[0] = cvt_pk_bf16(v[0], v[1]);
    o[1] = cvt_pk_bf16(v[2], v[3]);
    o[2] = cvt_pk_bf16(v[4], v[5]);
    o[3] = cvt_pk_bf16(v[6], v[7]);
    *(i32x4*)&ao[base] = o;
}

extern "C" void kernel_launch(void* const* d_in, const int* in_sizes, int n_in,
                              void* d_out, int out_size, void* d_ws, size_t ws_size,
                              hipStream_t stream) {
    const float* x  = (const float*)d_in[0];
    const float* wq = (const float*)d_in[1];
    const float* bq = (const float*)d_in[2];
    const float* wk = (const float*)d_in[3];
    const float* bk = (const float*)d_in[4];
    const float* wv = (const float*)d_in[5];
    const float* bv = (const float*)d_in[6];
    const float* wo = (const float*)d_in[7];
    const float* bo = (const float*)d_in[8];
    const float* rb = (const float*)d_in[9];

    char* ws = (char*)d_ws;
    short* xb   = (short*)(ws);                 // 8 MB (reused as ao after attention)
    short* wqkv = (short*)(ws + (8u  << 20));   // 6 MB = wqt|wkt|wvt contiguous
    short* wot  = (short*)(ws + (14u << 20));   // 2 MB
    short* qb   = (short*)(ws + (16u << 20));   // 8 MB
    short* kb   = (short*)(ws + (24u << 20));   // 8 MB
    f32x4* bqt  = (f32x4*)(ws + (32u << 20));   // 1 MB
    short* vt   = (short*)(ws + (40u << 20));   // 8 MB (written directly by gemm_qkv)
    short* po   = (short*)(ws + (48u << 20));   // 16 MB bf16 partial O [2][4096][1024]
    float* pl   = (float*)(ws + (64u << 20));   // 512 KB f32 partial l [2][4096][16]
    short* ao   = xb;

    prep_all<<<5376, 256, 0, stream>>>(x, wq, wk, wv, wo, rb, xb, wqkv, wot, bqt);

    gemm_qkv<<<1536, 256, 0, stream>>>(xb, wqkv, bq, bk, bv, qb, kb, vt);

    attn_partial<<<1024, 256, 0, stream>>>(qb, kb, vt, bqt, po, pl);
    attn_merge<<<2048, 256, 0, stream>>>(po, pl, ao);

    gemm_bias<3><<<512, 256, 0, stream>>>(ao, wot, bo, (float*)d_out);
}

// Round 22
// 127.044 us; speedup vs baseline: 1.0088x; 1.0025x over previous
//
#include <hip/hip_runtime.h>
#include <hip/hip_bf16.h>

#define D_MODEL 1024
#define NHEADS  16
#define HEADD   64
#define SEQ     2048
#define PERIOD  4096
#define LOG2E   1.44269504088896340736f

typedef __attribute__((ext_vector_type(4)))  float f32x4;
typedef __attribute__((ext_vector_type(16))) float f32x16;
typedef __attribute__((ext_vector_type(4)))  float fvec4;
typedef __attribute__((ext_vector_type(8)))  short s16x8;
typedef __attribute__((ext_vector_type(4)))  short s16x4;
typedef __attribute__((ext_vector_type(2)))  int   i32x2;
typedef __attribute__((ext_vector_type(4)))  int   i32x4;

__device__ __forceinline__ short bf16_bits(float f) {
    union { float f; unsigned u; } v; v.f = f;
    unsigned r = v.u + 0x7FFFu + ((v.u >> 16) & 1u);   // RNE
    return (short)(r >> 16);
}

__device__ __forceinline__ int cvt_pk_bf16(float a, float b) {
    int r;
    asm("v_cvt_pk_bf16_f32 %0, %1, %2" : "=v"(r) : "v"(a), "v"(b));
    return r;
}

__device__ __forceinline__ float bf16_to_f32(short s) {
    return __int_as_float(((int)(unsigned short)s) << 16);
}

__device__ __forceinline__ float exp2_hw(float x) {
    float r;
    asm("v_exp_f32 %0, %1" : "=v"(r) : "v"(x));   // bare 2^x, no OCML range code
    return r;
}

__device__ __forceinline__ void gload_lds16(const void* g, void* l) {
    __builtin_amdgcn_global_load_lds(
        (const __attribute__((address_space(1))) void*)g,
        (__attribute__((address_space(3))) void*)l, 16, 0, 0);
}

// ---------------- fused prep: cvt_x | transpose_w4 | build_biasq ----------------
// biasq table is pre-ROTATED by +2051: entry a' = old[(a'-2051)&4095], so the attn
// kernel indexes with qrow-kq-3+2051 (always in [4,4095]) and needs NO mod mask.
__global__ void prep_all(const float* __restrict__ x,
                         const float* __restrict__ wq, const float* __restrict__ wk,
                         const float* __restrict__ wv, const float* __restrict__ wo,
                         const float* __restrict__ rb,
                         short* __restrict__ xb, short* __restrict__ wqkv,
                         short* __restrict__ wot, f32x4* __restrict__ bq4) {
    __shared__ float tile[64][65];
    int bid = blockIdx.x;
    int t = threadIdx.x;
    if (bid < 4096) {
        int i = bid * 256 + t;
        fvec4 v = ((const fvec4*)x)[i];
        s16x4 o;
        o.x = bf16_bits(v.x); o.y = bf16_bits(v.y);
        o.z = bf16_bits(v.z); o.w = bf16_bits(v.w);
        ((s16x4*)xb)[i] = o;
    } else if (bid < 5120) {
        int b2 = bid - 4096;
        int wsel = b2 >> 8;
        int bxy = b2 & 255;
        const float* src = wsel == 0 ? wq : (wsel == 1 ? wk : (wsel == 2 ? wv : wo));
        short* dst = wsel < 3 ? wqkv + wsel * 1024 * 1024 : wot;
        int bx = bxy & 15, by = bxy >> 4;
        int n0 = bx * 64, k0 = by * 64;
        int cr = t >> 4;
        int cc = (t & 15) * 4;
        for (int i = 0; i < 4; ++i) {
            int row = cr + i * 16;
            fvec4 v = *(const fvec4*)&src[(k0 + row) * D_MODEL + n0 + cc];
            tile[row][cc+0] = v.x; tile[row][cc+1] = v.y;
            tile[row][cc+2] = v.z; tile[row][cc+3] = v.w;
        }
        __syncthreads();
        for (int i = 0; i < 4; ++i) {
            int row = cr + i * 16;
            s16x4 o;
            o.x = bf16_bits(tile[cc+0][row]);
            o.y = bf16_bits(tile[cc+1][row]);
            o.z = bf16_bits(tile[cc+2][row]);
            o.w = bf16_bits(tile[cc+3][row]);
            *(s16x4*)&dst[(n0 + row) * D_MODEL + k0 + cc] = o;
        }
    } else {
        int id = (bid - 5120) * 256 + t;    // 0..65535 = h*4096 + a'
        int h = id >> 12, a = id & 4095;
        f32x4 v;
        #pragma unroll
        for (int j = 0; j < 4; ++j)
            v[j] = rb[((a - 2051 + j) & (PERIOD - 1)) * NHEADS + h] * LOG2E - 16.0f;
        bq4[id] = v;
    }
}

// ---------------- fused QKV GEMM (r16-proven) + direct transposed V output ----------------
__global__ __launch_bounds__(256, 3) void gemm_qkv(
    const short* __restrict__ A, const short* __restrict__ Bt,
    const float* __restrict__ biasq, const float* __restrict__ biask,
    const float* __restrict__ biasv,
    short* __restrict__ qb, short* __restrict__ kb, short* __restrict__ vt)
{
    __shared__ short As[2][128 * 64];   // 2 x 16 KB
    __shared__ short Bs[2][64 * 64];    // 2 x  8 KB
    int tid = threadIdx.x;
    int lane = tid & 63, wid = tid >> 6;
    int ln = lane & 15, g = lane >> 4;
    int wr = (wid >> 1) * 64, wc = (wid & 1) * 32;

    int bid = blockIdx.x;
    int xcd = bid & 7, slot = bid >> 3;        // slot 0..191
    int mb = xcd * 4 + (slot / 48);            // 0..31
    int nb = slot % 48;                        // 0..47
    int m0 = mb * 128, n0 = nb * 64;

    int wsel = n0 >> 10;                       // 0:q 1:k 2:v
    const float* bias = wsel == 0 ? biasq : (wsel == 1 ? biask : biasv);
    float osc = wsel == 0 ? (0.125f * LOG2E) : 1.0f;
    int ncol0 = n0 & 1023;

    f32x4 acc[4][2] = {};

    auto STAGE = [&](int kt, int bi) {
        #pragma unroll
        for (int i = 0; i < 4; ++i) {
            int idx = i * 256 + tid;
            int row = idx >> 3, ch = idx & 7;
            int gch = ch ^ (row & 7);
            gload_lds16(&A[(m0 + row) * 1024 + kt + gch * 8],
                        (char*)&As[bi][0] + (i * 256 + wid * 64) * 16);
        }
        #pragma unroll
        for (int i = 0; i < 2; ++i) {
            int idx = i * 256 + tid;
            int row = idx >> 3, ch = idx & 7;
            int gch = ch ^ (row & 7);
            gload_lds16(&Bt[(n0 + row) * 1024 + kt + gch * 8],
                        (char*)&Bs[bi][0] + (i * 256 + wid * 64) * 16);
        }
    };

    STAGE(0, 0);
    __syncthreads();

    for (int kt = 0; kt < 16; ++kt) {
        int bi = kt & 1;
        if (kt < 15) STAGE((kt + 1) * 64, bi ^ 1);

        s16x8 af[4][2], bfr[2][2];
        #pragma unroll
        for (int m = 0; m < 4; ++m) {
            int row = wr + m * 16 + ln;
            #pragma unroll
            for (int kc = 0; kc < 2; ++kc)
                af[m][kc] = *(const s16x8*)&As[bi][row * 64 + (((kc * 4 + g) ^ (row & 7)) * 8)];
        }
        #pragma unroll
        for (int n = 0; n < 2; ++n) {
            int row = wc + n * 16 + ln;
            #pragma unroll
            for (int kc = 0; kc < 2; ++kc)
                bfr[n][kc] = *(const s16x8*)&Bs[bi][row * 64 + (((kc * 4 + g) ^ (row & 7)) * 8)];
        }
        #pragma unroll
        for (int kc = 0; kc < 2; ++kc)
            #pragma unroll
            for (int m = 0; m < 4; ++m)
                #pragma unroll
                for (int n = 0; n < 2; ++n)
                    acc[m][n] = __builtin_amdgcn_mfma_f32_16x16x32_bf16(af[m][kc], bfr[n][kc], acc[m][n], 0, 0, 0);

        __syncthreads();
    }

    if (wsel == 2) {
        // direct transposed V: vt[(b*1024 + gc)*2048 + s0 + r], r contiguous
        #pragma unroll
        for (int m = 0; m < 4; ++m) {
            int gr0 = m0 + wr + m * 16 + g * 4;
            int b = gr0 >> 11, s0 = gr0 & 2047;
            #pragma unroll
            for (int n = 0; n < 2; ++n) {
                int gc = ncol0 + wc + n * 16 + ln;
                float bvv = bias[gc];
                i32x2 st;
                st[0] = cvt_pk_bf16(acc[m][n][0] + bvv, acc[m][n][1] + bvv);
                st[1] = cvt_pk_bf16(acc[m][n][2] + bvv, acc[m][n][3] + bvv);
                *(i32x2*)&vt[(b * 1024 + gc) * 2048 + s0] = st;
            }
        }
    } else {
        short* dst = wsel == 0 ? qb : kb;
        #pragma unroll
        for (int m = 0; m < 4; ++m) {
            int gr0 = m0 + wr + m * 16 + g * 4;
            #pragma unroll
            for (int n = 0; n < 2; ++n) {
                int gc = ncol0 + wc + n * 16 + ln;
                float bvv = bias[gc];
                #pragma unroll
                for (int r = 0; r < 4; ++r)
                    dst[(gr0 + r) * 1024 + gc] = bf16_bits((acc[m][n][r] + bvv) * osc);
            }
        }
    }
}

// ---------------- GEMM: C = A[M,1024]b @ Bt[n][k]b + bias (MODE 3: f32 out) ----------------
template<int MODE>
__global__ __launch_bounds__(256) void gemm_bias(
    const short* __restrict__ A, const short* __restrict__ Bt,
    const float* __restrict__ bias, void* __restrict__ Cout)
{
    __shared__ short As[2][128 * 64];
    __shared__ short Bs[2][64 * 64];
    int tid = threadIdx.x;
    int lane = tid & 63, wid = tid >> 6;
    int ln = lane & 15, g = lane >> 4;
    int wr = (wid >> 1) * 64, wc = (wid & 1) * 32;

    int bid = blockIdx.x;                 // 0..511
    int xcd = bid & 7, slot = bid >> 3;
    int mb = xcd * 4 + (slot >> 4);
    int nb = slot & 15;
    int m0 = mb * 128, n0 = nb * 64;

    f32x4 acc[4][2] = {};

    auto STAGE = [&](int kt, int bi) {
        #pragma unroll
        for (int i = 0; i < 4; ++i) {
            int idx = i * 256 + tid;
            int row = idx >> 3, ch = idx & 7;
            int gch = ch ^ (row & 7);
            gload_lds16(&A[(m0 + row) * 1024 + kt + gch * 8],
                        (char*)&As[bi][0] + (i * 256 + wid * 64) * 16);
        }
        #pragma unroll
        for (int i = 0; i < 2; ++i) {
            int idx = i * 256 + tid;
            int row = idx >> 3, ch = idx & 7;
            int gch = ch ^ (row & 7);
            gload_lds16(&Bt[(n0 + row) * 1024 + kt + gch * 8],
                        (char*)&Bs[bi][0] + (i * 256 + wid * 64) * 16);
        }
    };

    STAGE(0, 0);
    __syncthreads();

    for (int kt = 0; kt < 16; ++kt) {
        int bi = kt & 1;
        if (kt < 15) STAGE((kt + 1) * 64, bi ^ 1);

        s16x8 af[4][2], bfr[2][2];
        #pragma unroll
        for (int m = 0; m < 4; ++m) {
            int row = wr + m * 16 + ln;
            #pragma unroll
            for (int kc = 0; kc < 2; ++kc)
                af[m][kc] = *(const s16x8*)&As[bi][row * 64 + (((kc * 4 + g) ^ (row & 7)) * 8)];
        }
        #pragma unroll
        for (int n = 0; n < 2; ++n) {
            int row = wc + n * 16 + ln;
            #pragma unroll
            for (int kc = 0; kc < 2; ++kc)
                bfr[n][kc] = *(const s16x8*)&Bs[bi][row * 64 + (((kc * 4 + g) ^ (row & 7)) * 8)];
        }
        #pragma unroll
        for (int kc = 0; kc < 2; ++kc)
            #pragma unroll
            for (int m = 0; m < 4; ++m)
                #pragma unroll
                for (int n = 0; n < 2; ++n)
                    acc[m][n] = __builtin_amdgcn_mfma_f32_16x16x32_bf16(af[m][kc], bfr[n][kc], acc[m][n], 0, 0, 0);

        __syncthreads();
    }

    #pragma unroll
    for (int m = 0; m < 4; ++m) {
        int gr0 = m0 + wr + m * 16 + g * 4;
        #pragma unroll
        for (int n = 0; n < 2; ++n) {
            int gc = n0 + wc + n * 16 + ln;
            float bv = bias[gc];
            #pragma unroll
            for (int r = 0; r < 4; ++r) {
                int gr = gr0 + r;
                float v = acc[m][n][r] + bv;
                if (MODE == 0)      ((short*)Cout)[gr * 1024 + gc] = bf16_bits(v * (0.125f * LOG2E));
                else if (MODE == 1) ((short*)Cout)[gr * 1024 + gc] = bf16_bits(v);
                else                ((float*)Cout)[gr * 1024 + gc] = v;
            }
        }
    }
}

// ---------------- attention partial: rotated bias table, mask-free affine index ----------------
__global__ __launch_bounds__(256, 2) void attn_partial(
    const short* __restrict__ qb,     // [4096][1024], pre-scaled by 0.125*log2e
    const short* __restrict__ kb,     // [4096][1024]
    const short* __restrict__ vt,     // [(b*1024+h*64+d)][2048]
    const f32x4* __restrict__ biasq,  // [16][4096], rotated by +2051, log2 domain - 16
    short* __restrict__ po,           // [2][4096][1024] bf16 partial O
    float* __restrict__ pl)           // [2][4096][16]  f32 partial l
{
    __shared__ short KV[2][2][64 * 64];   // [buf][0=K,1=V] = 32 KB

    int tid = threadIdx.x;
    int lane = tid & 63;
    int wid = tid >> 6;                   // 0..3
    int l31 = lane & 31, hi = lane >> 5;

    // XCD swizzle: all 32 blocks of one (h,b) pinned to one XCD (bijective: 8*4*32 = 1024)
    int bid = blockIdx.x;
    int xcd = bid & 7, slot = bid >> 3;   // 0..127
    int hb = xcd * 4 + (slot >> 5);       // 0..31
    int qt = (slot >> 1) & 15;
    int half = slot & 1;
    int h = hb & 15, b = hb >> 4;
    int q0 = qt * 128 + wid * 32;
    int qrow = q0 + l31;
    int kbase = half * 1024;

    // Q fragments (B-operand: col=q, k-contiguous)
    s16x8 aq[4];
    #pragma unroll
    for (int kk = 0; kk < 4; ++kk)
        aq[kk] = *(const s16x8*)&qb[(b * SEQ + qrow) * D_MODEL + h * HEADD + kk * 16 + hi * 8];

    // mask-free bias base: index qrow-kq-3+2051 in [4,4095] for all tiles (no wrap)
    const f32x4* bq = biasq + h * PERIOD + (qrow - kbase - hi * 4 + 2048);

    float lrow = 0.f;
    f32x16 ot[2] = {};

    auto STAGE = [&](int k0, int bi) {   // k0 absolute key index
        #pragma unroll
        for (int i = 0; i < 2; ++i) {
            int idx = i * 256 + tid;
            int row = idx >> 3, ch = idx & 7;
            int gch = ch ^ ((row & 7) ^ ((row >> 3) & 3));
            gload_lds16(&kb[(b * SEQ + k0 + row) * D_MODEL + h * HEADD + gch * 8],
                        (char*)&KV[bi][0][0] + (i * 256 + wid * 64) * 16);
            gload_lds16(&vt[(b * D_MODEL + h * HEADD + row) * SEQ + k0 + gch * 8],
                        (char*)&KV[bi][1][0] + (i * 256 + wid * 64) * 16);
        }
    };

    STAGE(kbase, 0);
    __syncthreads();

    for (int kt = 0; kt < 16; ++kt) {
        int k0 = kbase + kt * 64;
        int bi = kt & 1;
        if (kt < 15) STAGE(k0 + 64, bi ^ 1);   // prefetch next K/V tile

        // bias gathers: affine index (no mask), issued early to overlap MFMA
        f32x4 bv[2][4];
        #pragma unroll
        for (int kt32 = 0; kt32 < 2; ++kt32)
            #pragma unroll
            for (int rq = 0; rq < 4; ++rq)
                bv[kt32][rq] = bq[-(kt * 64 + kt32 * 32 + rq * 8)];

        // S^T = K · Q^T  (rows=k, cols=q), log2 domain
        f32x16 s[2];
        const short* Ksp = &KV[bi][0][0];
        const short* Vsp = &KV[bi][1][0];
        __builtin_amdgcn_s_setprio(1);
        #pragma unroll
        for (int kt32 = 0; kt32 < 2; ++kt32) {
            f32x16 acc = {};
            int rowK = kt32 * 32 + l31;
            int swz = (rowK & 7) ^ ((rowK >> 3) & 3);
            #pragma unroll
            for (int kk = 0; kk < 4; ++kk) {
                s16x8 kf = *(const s16x8*)&Ksp[rowK * 64 + (((2 * kk + hi) ^ swz) * 8)];
                acc = __builtin_amdgcn_mfma_f32_32x32x16_bf16(kf, aq[kk], acc, 0, 0, 0);
            }
            s[kt32] = acc;
        }
        __builtin_amdgcn_s_setprio(0);

        // p = exp2(score + bias - 16): fixed-max softmax
        #pragma unroll
        for (int kt32 = 0; kt32 < 2; ++kt32)
            #pragma unroll
            for (int rq = 0; rq < 4; ++rq) {
                s[kt32][rq * 4 + 0] = exp2_hw(s[kt32][rq * 4 + 0] + bv[kt32][rq][3]);
                s[kt32][rq * 4 + 1] = exp2_hw(s[kt32][rq * 4 + 1] + bv[kt32][rq][2]);
                s[kt32][rq * 4 + 2] = exp2_hw(s[kt32][rq * 4 + 2] + bv[kt32][rq][1]);
                s[kt32][rq * 4 + 3] = exp2_hw(s[kt32][rq * 4 + 3] + bv[kt32][rq][0]);
            }

        // l accumulation: tree over 32 in-lane values + cross-half partner add
        float sm[16];
        #pragma unroll
        for (int t = 0; t < 16; ++t) sm[t] = s[0][t] + s[1][t];
        #pragma unroll
        for (int t = 0; t < 8; ++t) sm[t] += sm[t + 8];
        #pragma unroll
        for (int t = 0; t < 4; ++t) sm[t] += sm[t + 4];
        float psum = (sm[0] + sm[1]) + (sm[2] + sm[3]);
        {
            i32x2 r = __builtin_amdgcn_permlane32_swap(__float_as_int(psum), __float_as_int(psum), false, false);
            psum = __int_as_float(r[0]) + __int_as_float(r[1]);
        }
        lrow += psum;

        // P repack via permlane32_swap (VALU, no LDS) + PV: O^T += V^T . P
        #pragma unroll
        for (int kt32 = 0; kt32 < 2; ++kt32) {
            int pk[8];
            #pragma unroll
            for (int i = 0; i < 8; ++i)
                pk[i] = cvt_pk_bf16(s[kt32][2 * i], s[kt32][2 * i + 1]);
            #pragma unroll
            for (int ks = 0; ks < 2; ++ks) {
                int a0 = pk[ks * 4 + 0], a1 = pk[ks * 4 + 1];
                int b0 = pk[ks * 4 + 2], b1 = pk[ks * 4 + 3];
                i32x2 r0 = __builtin_amdgcn_permlane32_swap(a0, b0, false, false);
                i32x2 r1 = __builtin_amdgcn_permlane32_swap(a1, b1, false, false);
                i32x4 wi;
                wi[0] = r0[0];   // k = hi*8 + 0,1
                wi[1] = r1[0];   // k = hi*8 + 2,3
                wi[2] = r0[1];   // k = hi*8 + 4,5
                wi[3] = r1[1];   // k = hi*8 + 6,7
                s16x8 pb = __builtin_bit_cast(s16x8, wi);
                __builtin_amdgcn_s_setprio(1);
                #pragma unroll
                for (int dd = 0; dd < 2; ++dd) {
                    int rowV = dd * 32 + l31;
                    int swzV = (rowV & 7) ^ ((rowV >> 3) & 3);
                    int chV = kt32 * 4 + ks * 2 + hi;
                    s16x8 vf = *(const s16x8*)&Vsp[rowV * 64 + ((chV ^ swzV) * 8)];
                    ot[dd] = __builtin_amdgcn_mfma_f32_32x32x16_bf16(vf, pb, ot[dd], 0, 0, 0);
                }
                __builtin_amdgcn_s_setprio(0);
            }
        }

        __syncthreads();   // prefetch landed; all readers done
    }

    // epilogue: write bf16 partials (no divide; merge kernel finishes)
    short* poH = po + half * (4096 * 1024);
    int obase = (b * SEQ + qrow) * D_MODEL + h * HEADD;
    #pragma unroll
    for (int dd = 0; dd < 2; ++dd)
        #pragma unroll
        for (int rq = 0; rq < 4; ++rq) {
            i32x2 st;
            st[0] = cvt_pk_bf16(ot[dd][rq * 4 + 0], ot[dd][rq * 4 + 1]);
            st[1] = cvt_pk_bf16(ot[dd][rq * 4 + 2], ot[dd][rq * 4 + 3]);
            *(i32x2*)&poH[obase + dd * 32 + rq * 8 + hi * 4] = st;
        }
    if (hi == 0)
        pl[half * (4096 * 16) + (b * SEQ + qrow) * 16 + h] = lrow;
}

// ---------------- merge: ao = (po0+po1)/(pl0+pl1) -> bf16 ----------------
__global__ __launch_bounds__(256) void attn_merge(
    const short* __restrict__ po, const float* __restrict__ pl,
    short* __restrict__ ao)
{
    int idx = blockIdx.x * 256 + threadIdx.x;
    int base = idx * 8;                 // 8 consecutive cols, never crosses a head
    int row = base >> 10, col = base & 1023, h = col >> 6;
    float l = pl[row * 16 + h] + pl[4096 * 16 + row * 16 + h];
    float inv = 1.0f / l;
    s16x8 a = *(const s16x8*)&po[row * 1024 + col];
    s16x8 c = *(const s16x8*)&po[4096 * 1024 + row * 1024 + col];
    float v[8];
    #pragma unroll
    for (int j = 0; j < 8; ++j)
        v[j] = (bf16_to_f32(a[j]) + bf16_to_f32(c[j])) * inv;
    i32x4 o;
    o[0] = cvt_pk_bf16(v[0], v[1]);
    o[1] = cvt_pk_bf16(v[2], v[3]);
    o[2] = cvt_pk_bf16(v[4], v[5]);
    o[3] = cvt_pk_bf16(v[6], v[7]);
    *(i32x4*)&ao[base] = o;
}

extern "C" void kernel_launch(void* const* d_in, const int* in_sizes, int n_in,
                              void* d_out, int out_size, void* d_ws, size_t ws_size,
                              hipStream_t stream) {
    const float* x  = (const float*)d_in[0];
    const float* wq = (const float*)d_in[1];
    const float* bq = (const float*)d_in[2];
    const float* wk = (const float*)d_in[3];
    const float* bk = (const float*)d_in[4];
    const float* wv = (const float*)d_in[5];
    const float* bv = (const float*)d_in[6];
    const float* wo = (const float*)d_in[7];
    const float* bo = (const float*)d_in[8];
    const float* rb = (const float*)d_in[9];

    char* ws = (char*)d_ws;
    short* xb   = (short*)(ws);                 // 8 MB (reused as ao after attention)
    short* wqkv = (short*)(ws + (8u  << 20));   // 6 MB = wqt|wkt|wvt contiguous
    short* wot  = (short*)(ws + (14u << 20));   // 2 MB
    short* qb   = (short*)(ws + (16u << 20));   // 8 MB
    short* kb   = (short*)(ws + (24u << 20));   // 8 MB
    f32x4* bqt  = (f32x4*)(ws + (32u << 20));   // 1 MB (rotated table)
    short* vt   = (short*)(ws + (40u << 20));   // 8 MB (written directly by gemm_qkv)
    short* po   = (short*)(ws + (48u << 20));   // 16 MB bf16 partial O [2][4096][1024]
    float* pl   = (float*)(ws + (64u << 20));   // 512 KB f32 partial l [2][4096][16]
    short* ao   = xb;

    prep_all<<<5376, 256, 0, stream>>>(x, wq, wk, wv, wo, rb, xb, wqkv, wot, bqt);

    gemm_qkv<<<1536, 256, 0, stream>>>(xb, wqkv, bq, bk, bv, qb, kb, vt);

    attn_partial<<<1024, 256, 0, stream>>>(qb, kb, vt, bqt, po, pl);
    attn_merge<<<2048, 256, 0, stream>>>(po, pl, ao);

    gemm_bias<3><<<512, 256, 0, stream>>>(ao, wot, bo, (float*)d_out);
}